// Round 1
// baseline (76.816 us; speedup 1.0000x reference)
//
#include <hip/hip_runtime.h>

namespace {
constexpr int kBS = 8, kNV = 16, kMF = 16, kMT = 16, kNP = 8, kNR = 12;
constexpr int kH = 64, kNOUT = 64;
constexpr int kRelCell = kNP * 3 * kNR; // 288 floats per cell
}

__device__ __forceinline__ float readlane_f(float v, int l) {
    union { float f; int i; } u; u.f = v;
    u.i = __builtin_amdgcn_readlane(u.i, l);
    return u.f;
}

// block: 256 threads = 4 waves; each wave handles 4 (t,f) cells of one (b,v).
// grid: 128 (b,v) * 16 chunks = 2048 blocks.
__global__ __launch_bounds__(256, 4) void gal_kernel(
    const float* __restrict__ rel,      // (BS,NV,MF,MT,NP,K,NR)
    const float* __restrict__ se,       // (BS,NV,MT,MF,H)
    const float* __restrict__ s,        // (BS,NV,NOUT)
    const float* __restrict__ Wstack,   // (NR,H,H)
    const float* __restrict__ lin_w,    // (1,H+NOUT)
    const float* __restrict__ lin_b,    // (1,)
    const float* __restrict__ out_w,    // (NOUT,H)
    const float* __restrict__ out_b,    // (NOUT,)
    float* __restrict__ out)            // (BS,NV,NOUT)
{
    __shared__ __align__(16) float wT[kH * kNOUT];        // wT[d*64+o] = out_w[o][d]
    __shared__ __align__(16) float relbuf[4][2][kRelCell]; // per-wave double buffer

    const int tid  = (int)threadIdx.x;
    const int lane = tid & 63;
    const int w    = tid >> 6;

    // out_w transposed into LDS (once per block)
    for (int i = tid; i < kH * kNOUT; i += 256) {
        const int o = i >> 6, d = i & 63;
        wT[d * kNOUT + o] = out_w[i];
    }

    const int bv    = (int)blockIdx.x >> 4;   // 0..127
    const int chunk = (int)blockIdx.x & 15;   // 16 cells per block

    // per-lane (lane = d) constants
    float dreg[kNR];
#pragma unroll
    for (int r = 0; r < kNR; ++r)
        dreg[r] = Wstack[r * kH * kH + lane * (kH + 1)];  // diag

    const float wz = lin_w[kNOUT + lane];
    float sv = s[bv * kNOUT + lane] * lin_w[lane];
#pragma unroll
    for (int m = 1; m < 64; m <<= 1) sv += __shfl_xor(sv, m, 64);
    const float logit_base = sv + lin_b[0];
    const float ob = out_b[lane];   // lane = o in the epilogue

    __syncthreads();  // wT ready

    const int cell0 = chunk * 16 + w * 4;
    float zreg0 = 0.f, zreg1 = 0.f, zreg2 = 0.f, zreg3 = 0.f;

#pragma unroll
    for (int i = 0; i < 4; ++i) {
        const int cell = cell0 + i;
        const int t = cell >> 4, f = cell & 15;

        // stage this cell's 288 rel floats into wave-private LDS (coalesced)
        const float* rp = rel + (size_t)((bv * kMF + f) * kMT + t) * kRelCell;
        float* rb = relbuf[w][i & 1];
#pragma unroll
        for (int j = 0; j < 4; ++j) rb[lane + j * 64] = rp[lane + j * 64];
        if (lane < 32) rb[256 + lane] = rp[256 + lane];
        // wave-private buffer: compiler-inserted lgkmcnt ordering, no barrier

        const float sev = se[(size_t)((bv * kMT + t) * kMF + f) * kH + lane];

        float zj[kNP], lg[kNP];
#pragma unroll
        for (int p = 0; p < kNP; ++p) {
            const float4* r4 = (const float4*)(rb + p * 36);
            const float4 a0 = r4[0], a1 = r4[1], a2 = r4[2];
            const float4 b0 = r4[3], b1 = r4[4], b2 = r4[5];
            const float4 c0 = r4[6], c1 = r4[7], c2 = r4[8];
            float d0 = a0.x*dreg[0] + a0.y*dreg[1] + a0.z*dreg[2] + a0.w*dreg[3]
                     + a1.x*dreg[4] + a1.y*dreg[5] + a1.z*dreg[6] + a1.w*dreg[7]
                     + a2.x*dreg[8] + a2.y*dreg[9] + a2.z*dreg[10] + a2.w*dreg[11];
            float d1 = b0.x*dreg[0] + b0.y*dreg[1] + b0.z*dreg[2] + b0.w*dreg[3]
                     + b1.x*dreg[4] + b1.y*dreg[5] + b1.z*dreg[6] + b1.w*dreg[7]
                     + b2.x*dreg[8] + b2.y*dreg[9] + b2.z*dreg[10] + b2.w*dreg[11];
            float d2 = c0.x*dreg[0] + c0.y*dreg[1] + c0.z*dreg[2] + c0.w*dreg[3]
                     + c1.x*dreg[4] + c1.y*dreg[5] + c1.z*dreg[6] + c1.w*dreg[7]
                     + c2.x*dreg[8] + c2.y*dreg[9] + c2.z*dreg[10] + c2.w*dreg[11];
            const float wd = d0 * d1 * d2;
            const float z = wd * sev;
            zj[p] = z;
            float la = z * wz;
#pragma unroll
            for (int m = 1; m < 64; m <<= 1) la += __shfl_xor(la, m, 64);
            lg[p] = la + logit_base;
        }

        // softmax over p (identical in all lanes)
        float mx = lg[0];
#pragma unroll
        for (int p = 1; p < kNP; ++p) mx = fmaxf(mx, lg[p]);
        float e[kNP], esum = 0.f;
#pragma unroll
        for (int p = 0; p < kNP; ++p) { e[p] = __expf(lg[p] - mx); esum += e[p]; }
        const float inv = 1.0f / esum;
        float zd = 0.f;
#pragma unroll
        for (int p = 0; p < kNP; ++p) zd = fmaf(e[p] * inv, zj[p], zd);

        if      (i == 0) zreg0 = zd;
        else if (i == 1) zreg1 = zd;
        else if (i == 2) zreg2 = zd;
        else             zreg3 = zd;
    }

    // batched 64x64 matvec for the wave's 4 cells; lane = o
    float q0 = 0.f, q1 = 0.f, q2 = 0.f, q3 = 0.f;
#pragma unroll
    for (int d = 0; d < kH; ++d) {
        const float wv = wT[d * kNOUT + lane];
        q0 = fmaf(readlane_f(zreg0, d), wv, q0);
        q1 = fmaf(readlane_f(zreg1, d), wv, q1);
        q2 = fmaf(readlane_f(zreg2, d), wv, q2);
        q3 = fmaf(readlane_f(zreg3, d), wv, q3);
    }
    const float tot = fmaxf(q0 + ob, 0.f) + fmaxf(q1 + ob, 0.f)
                    + fmaxf(q2 + ob, 0.f) + fmaxf(q3 + ob, 0.f);
    atomicAdd(&out[bv * kNOUT + lane], tot);
}

extern "C" void kernel_launch(void* const* d_in, const int* in_sizes, int n_in,
                              void* d_out, int out_size, void* d_ws, size_t ws_size,
                              hipStream_t stream) {
    const float* rel   = (const float*)d_in[0];
    const float* sem   = (const float*)d_in[1];
    const float* s     = (const float*)d_in[2];
    const float* Wst   = (const float*)d_in[3];
    const float* lin_w = (const float*)d_in[4];
    const float* lin_b = (const float*)d_in[5];
    const float* out_w = (const float*)d_in[6];
    const float* out_b = (const float*)d_in[7];
    float* out = (float*)d_out;

    hipMemsetAsync(out, 0, sizeof(float) * kBS * kNV * kNOUT, stream);
    dim3 grid(kBS * kNV * 16), block(256);
    hipLaunchKernelGGL(gal_kernel, grid, block, 0, stream,
                       rel, sem, s, Wst, lin_w, lin_b, out_w, out_b, out);
}